// Round 10
// baseline (265.080 us; speedup 1.0000x reference)
//
#include <hip/hip_runtime.h>
#include <stdint.h>

typedef __bf16 bf16_t;
typedef __bf16 bf16x8 __attribute__((ext_vector_type(8)));
typedef __bf16 bf16x4 __attribute__((ext_vector_type(4)));
typedef float floatx4 __attribute__((ext_vector_type(4)));

__device__ __forceinline__ void async_copy16(const bf16_t* g, bf16_t* l) {
  __builtin_amdgcn_global_load_lds(
      (const __attribute__((address_space(1))) void*)g,
      (__attribute__((address_space(3))) void*)l, 16, 0, 0);
}

// ---------- converts ----------
struct CvtSeg { const float* s; bf16_t* d; long n; };
struct CvtArgs { CvtSeg seg[5]; };

__global__ void cvt_multi(CvtArgs a) {
  CvtSeg sg = a.seg[blockIdx.y];
#pragma unroll
  for (int it = 0; it < 4; it++) {
    long i = (((long)blockIdx.x + (long)it * 2048) * 256 + threadIdx.x) * 4;
    if (i < sg.n) {
      float4 f = *(const float4*)(sg.s + i);
      bf16x4 o;
      o[0] = (bf16_t)f.x; o[1] = (bf16_t)f.y; o[2] = (bf16_t)f.z; o[3] = (bf16_t)f.w;
      *(bf16x4*)(sg.d + i) = o;
    }
  }
}

// ---------- fused q / kT / vT: 128x128 tile, LDS dbuf, HALF-GRID (diagnostic split) ----------
// Identical per-block work to the proven ~60us kernel; grid split into two
// 256-block dispatches (mhalf 0/1) so downstream kernels rise into rocprof top-5.
__global__ __launch_bounds__(256, 2) void qkv3h(
    const bf16_t* __restrict__ xb,
    const bf16_t* __restrict__ Wq, const bf16_t* __restrict__ Wk, const bf16_t* __restrict__ Wv,
    const float* __restrict__ bq, const float* __restrict__ bk, const float* __restrict__ bv,
    bf16_t* __restrict__ qout, bf16_t* __restrict__ kT, bf16_t* __restrict__ vT,
    int mhalf) {
  __shared__ bf16_t As[2 * 4096];
  __shared__ bf16_t Bsh[3][2 * 4096];
  const int L = blockIdx.x;                  // 256 blocks
  const int V = (L & 7) * 32 + (L >> 3);     // XCD swizzle, bijective (256 = 8*32)
  const int batch = V >> 6;                  // 4 batches x 64 tiles
  const int rr_   = V & 63;
  const int n0 = (rr_ & 7) * 128;
  const int m0 = (mhalf * 8 + (rr_ >> 3)) * 128;

  const int tid = threadIdx.x, lane = tid & 63, w = tid >> 6;
  const int wr = w >> 1, wc = w & 1, quad = lane >> 4, lm = lane & 15;
  const int ar = lane >> 2;
  const int ak = (((lane & 3) ^ ((ar >> 1) & 3))) * 8;
  const int swz = (lm >> 1) & 3;

  const bf16_t* ag0 = xb + (long)batch * (2048L * 1024) + (long)(m0 + w * 16 + ar) * 1024 + ak;
  const bf16_t* ag1 = ag0 + 64L * 1024;
  const bf16_t* Wp[3] = {Wq, Wk, Wv};
  const bf16_t* bg0[3];
  const bf16_t* bg1[3];
#pragma unroll
  for (int p = 0; p < 3; p++) {
    bg0[p] = Wp[p] + (long)(n0 + w * 16 + ar) * 1024 + ak;
    bg1[p] = bg0[p] + 64L * 1024;
  }

  floatx4 acc[3][4][4];
#pragma unroll
  for (int p = 0; p < 3; p++)
#pragma unroll
    for (int r = 0; r < 4; r++)
#pragma unroll
      for (int c = 0; c < 4; c++)
        acc[p][r][c] = (floatx4){0.f, 0.f, 0.f, 0.f};

  {
    bf16_t* la = As + w * 512;
    async_copy16(ag0, la);
    async_copy16(ag1, la + 2048);
#pragma unroll
    for (int p = 0; p < 3; p++) {
      bf16_t* lb = Bsh[p] + w * 512;
      async_copy16(bg0[p], lb);
      async_copy16(bg1[p], lb + 2048);
    }
  }
  for (int i = 0; i < 32; i++) {
    __syncthreads();
    if (i + 1 < 32) {
      const int buf = (i + 1) & 1, k0 = (i + 1) * 32;
      bf16_t* la = As + buf * 4096 + w * 512;
      async_copy16(ag0 + k0, la);
      async_copy16(ag1 + k0, la + 2048);
#pragma unroll
      for (int p = 0; p < 3; p++) {
        bf16_t* lb = Bsh[p] + buf * 4096 + w * 512;
        async_copy16(bg0[p] + k0, lb);
        async_copy16(bg1[p] + k0, lb + 2048);
      }
    }
    const bf16_t* Ar = As + (i & 1) * 4096;
    bf16x8 afr[4];
#pragma unroll
    for (int r = 0; r < 4; r++)
      afr[r] = *(const bf16x8*)&Ar[(wr * 64 + r * 16 + lm) * 32 + (quad ^ swz) * 8];
#pragma unroll
    for (int p = 0; p < 3; p++) {
      const bf16_t* Br = Bsh[p] + (i & 1) * 4096;
      bf16x8 bfr[4];
#pragma unroll
      for (int c = 0; c < 4; c++)
        bfr[c] = *(const bf16x8*)&Br[(wc * 64 + c * 16 + lm) * 32 + (quad ^ swz) * 8];
#pragma unroll
      for (int r = 0; r < 4; r++)
#pragma unroll
        for (int c = 0; c < 4; c++)
          acc[p][r][c] = __builtin_amdgcn_mfma_f32_16x16x32_bf16(afr[r], bfr[c], acc[p][r][c], 0, 0, 0);
    }
  }

  const int rowBase = m0 + wr * 64, colBase = n0 + wc * 64;
  {
    bf16_t* C = qout + (long)batch * (2048L * 1024);
#pragma unroll
    for (int r = 0; r < 4; r++) {
      const int row = rowBase + r * 16 + quad * 4;
#pragma unroll
      for (int c = 0; c < 4; c++) {
        const int col = colBase + c * 16 + lm;
        const float bv_ = bq[col];
#pragma unroll
        for (int i = 0; i < 4; i++)
          C[(long)(row + i) * 1024 + col] = (bf16_t)(acc[0][r][c][i] + bv_);
      }
    }
  }
#pragma unroll
  for (int p = 1; p < 3; p++) {
    bf16_t* C = ((p == 1) ? kT : vT) + (long)batch * (1024L * 2048);
    const float* bias = (p == 1) ? bk : bv;
#pragma unroll
    for (int r = 0; r < 4; r++) {
      const int row = rowBase + r * 16 + quad * 4;
#pragma unroll
      for (int c = 0; c < 4; c++) {
        const int col = colBase + c * 16 + lm;
        const float bv_ = bias[col];
        bf16x4 pk;
#pragma unroll
        for (int i = 0; i < 4; i++) pk[i] = (bf16_t)(acc[p][r][c][i] + bv_);
        *(bf16x4*)(C + (long)col * 2048 + row) = pk;
      }
    }
  }
}

// ---------- NT GEMM, 128x128 tile, WAVE-PRIVATE barrier-free DEPTH-4 pipeline ----------
// (round-5 champion, verbatim.) Each wave stages its own 64x32 A-half and B-half
// into a private 32KB LDS slice (4 bufs). No s_barrier anywhere. Prefetch
// distance 3 K-steps; vmcnt ladder 24/16/8/0. LDS: static 128KB -> 1 block/CU.
// OUT_MODE 0: bf16 row-major; 2: fp32 row-major (+bias). N fixed at 1024.
template<int OUT_MODE, bool HAS_BIAS, int TOTAL, int BPZ>
__global__ __launch_bounds__(256) void gemm_wp(
    const bf16_t* __restrict__ A, const bf16_t* __restrict__ B,
    void* __restrict__ C, const float* __restrict__ bias,
    int lda, int ldb, int nk, long sA, long sB, long sC, int ldc, float alpha) {
  __shared__ bf16_t Ls[4 * 16384];  // 4 waves x 4 bufs x 4096 elems = 128KB static
  const int L = blockIdx.x;
  const int V = (L & 7) * (TOTAL / 8) + (L >> 3);
  const int batch = V / BPZ;
  const int r_ = V % BPZ;
  const int n0 = (r_ & 7) * 128;
  const int m0 = (r_ >> 3) * 128;

  const int tid = threadIdx.x, lane = tid & 63, w = tid >> 6;
  const int wr = w >> 1, wc = w & 1, quad = lane >> 4, lm = lane & 15;
  const int ar = lane >> 2;
  const int ak = (((lane & 3) ^ ((ar >> 1) & 3))) * 8;
  const int swz = (lm >> 1) & 3;

  bf16_t* Lw = Ls + w * 16384;
  const bf16_t* Ab = A + (long)batch * sA;
  const bf16_t* Bb = B + (long)batch * sB;
  const bf16_t* agA = Ab + (long)(m0 + wr * 64 + ar) * lda + ak;
  const bf16_t* agB = Bb + (long)(n0 + wc * 64 + ar) * ldb + ak;

  auto STAGE = [&](int t, int b) {
    const int k0 = t * 32;
    bf16_t* d = Lw + b * 4096;
#pragma unroll
    for (int j = 0; j < 4; j++)
      async_copy16(agA + (long)j * 16 * lda + k0, d + j * 512);
#pragma unroll
    for (int j = 0; j < 4; j++)
      async_copy16(agB + (long)j * 16 * ldb + k0, d + 2048 + j * 512);
  };

  floatx4 acc[4][4];
#pragma unroll
  for (int r = 0; r < 4; r++)
#pragma unroll
    for (int c = 0; c < 4; c++) acc[r][c] = (floatx4){0.f, 0.f, 0.f, 0.f};

  STAGE(0, 0);
  STAGE(1, 1);
  STAGE(2, 2);
  for (int i = 0; i < nk; i++) {
    const int rem = nk - 1 - i;
    if (rem >= 3) {
      STAGE(i + 3, (i + 3) & 3);
      asm volatile("s_waitcnt vmcnt(24)" ::: "memory");  // tile i's 8 loads done
    } else if (rem == 2) {
      asm volatile("s_waitcnt vmcnt(16)" ::: "memory");
    } else if (rem == 1) {
      asm volatile("s_waitcnt vmcnt(8)" ::: "memory");
    } else {
      asm volatile("s_waitcnt vmcnt(0)" ::: "memory");
    }
    const bf16_t* Aw = Lw + (i & 3) * 4096;
    const bf16_t* Bw = Aw + 2048;
    bf16x8 afr[4], bfr[4];
#pragma unroll
    for (int r = 0; r < 4; r++)
      afr[r] = *(const bf16x8*)&Aw[(r * 16 + lm) * 32 + (quad ^ swz) * 8];
#pragma unroll
    for (int c = 0; c < 4; c++)
      bfr[c] = *(const bf16x8*)&Bw[(c * 16 + lm) * 32 + (quad ^ swz) * 8];
#pragma unroll
    for (int r = 0; r < 4; r++)
#pragma unroll
      for (int c = 0; c < 4; c++)
        acc[r][c] = __builtin_amdgcn_mfma_f32_16x16x32_bf16(afr[r], bfr[c], acc[r][c], 0, 0, 0);
  }

  const int rowBase = m0 + wr * 64, colBase = n0 + wc * 64;
  if (OUT_MODE == 0) {
    bf16_t* Cb = (bf16_t*)C + (long)batch * sC;
#pragma unroll
    for (int r = 0; r < 4; r++) {
      const int row = rowBase + r * 16 + quad * 4;
#pragma unroll
      for (int c = 0; c < 4; c++) {
        const int col = colBase + c * 16 + lm;
        const float bv_ = HAS_BIAS ? bias[col] : 0.f;
#pragma unroll
        for (int i = 0; i < 4; i++)
          Cb[(long)(row + i) * ldc + col] = (bf16_t)(acc[r][c][i] * alpha + bv_);
      }
    }
  } else {
    float* Cf = (float*)C + (long)batch * sC;
#pragma unroll
    for (int r = 0; r < 4; r++) {
      const int row = rowBase + r * 16 + quad * 4;
#pragma unroll
      for (int c = 0; c < 4; c++) {
        const int col = colBase + c * 16 + lm;
        const float bv_ = HAS_BIAS ? bias[col] : 0.f;
#pragma unroll
        for (int i = 0; i < 4; i++)
          Cf[(long)(row + i) * ldc + col] = acc[r][c][i] * alpha + bv_;
      }
    }
  }
}

extern "C" void kernel_launch(void* const* d_in, const int* in_sizes, int n_in,
                              void* d_out, int out_size, void* d_ws, size_t ws_size,
                              hipStream_t stream) {
  const float* x  = (const float*)d_in[0];
  const float* Wq = (const float*)d_in[1];
  const float* bq = (const float*)d_in[2];
  const float* Wk = (const float*)d_in[3];
  const float* bk = (const float*)d_in[4];
  const float* Wv = (const float*)d_in[5];
  const float* bv = (const float*)d_in[6];
  const float* Wo = (const float*)d_in[7];
  const float* bo = (const float*)d_in[8];
  float* out = (float*)d_out;

  const long NX = 8192L * 1024;      // 8M elems
  const long NW = 1024L * 1024;      // 1M elems

  bf16_t* ws  = (bf16_t*)d_ws;
  bf16_t* xb  = ws;                  // NX
  bf16_t* Wqb = xb + NX;
  bf16_t* Wkb = Wqb + NW;
  bf16_t* Wvb = Wkb + NW;
  bf16_t* Wob = Wvb + NW;
  bf16_t* qb  = Wob + NW;            // NX
  bf16_t* kT  = qb + NX;             // NX [B][E][S]
  bf16_t* vT  = kT + NX;             // NX [B][E][S]
  // reuse (stream-ordered):
  bf16_t* MtTb = xb;                 // 4M: [B][f][e], xb dead after qkv3
  bf16_t* Gb   = vT;                 // 4M: [B][i][f], vT dead after M gemm

  CvtArgs ca;
  ca.seg[0] = {x,  xb,  NX};
  ca.seg[1] = {Wq, Wqb, NW};
  ca.seg[2] = {Wk, Wkb, NW};
  ca.seg[3] = {Wv, Wvb, NW};
  ca.seg[4] = {Wo, Wob, NW};
  cvt_multi<<<dim3(2048, 5), 256, 0, stream>>>(ca);

  // q / kT / vT fused, 128x128, split into two half-grids (diagnostic visibility)
  qkv3h<<<dim3(256), 256, 0, stream>>>(xb, Wqb, Wkb, Wvb, bq, bk, bv, qb, kT, vT, 0);
  qkv3h<<<dim3(256), 256, 0, stream>>>(xb, Wqb, Wkb, Wvb, bq, bk, bv, qb, kT, vT, 1);

  // MtT[f,e] = 0.125 * sum_t kT[f,t]*vT[e,t]; K=2048 (nk=64), 256 blocks (1/CU)
  gemm_wp<0, false, 256, 64><<<dim3(256), 256, 0, stream>>>(
      kT, vT, MtTb, nullptr, 2048, 2048, 64,
      1024L * 2048, 1024L * 2048, 1024L * 1024, 1024, 0.125f);

  // G[i,f] = sum_e Wo[i,e] * MtT[f,e]; 256 blocks (1/CU)
  gemm_wp<0, false, 256, 64><<<dim3(256), 256, 0, stream>>>(
      Wob, MtTb, Gb, nullptr, 1024, 1024, 32,
      0L, 1024L * 1024, 1024L * 1024, 1024, 1.0f);

  // out[s,i] = sum_f q[s,f] * G[i,f] + bo[i]; 512 blocks (1/CU, 2 passes)
  gemm_wp<2, true, 512, 128><<<dim3(512), 256, 0, stream>>>(
      qb, Gb, out, bo, 1024, 1024, 32,
      2048L * 1024, 1024L * 1024, 2048L * 1024, 1024, 1.0f);
}

// Round 11
// 235.701 us; speedup vs baseline: 1.1246x; 1.1246x over previous
//
#include <hip/hip_runtime.h>
#include <stdint.h>

typedef __bf16 bf16_t;
typedef __bf16 bf16x8 __attribute__((ext_vector_type(8)));
typedef __bf16 bf16x4 __attribute__((ext_vector_type(4)));
typedef float floatx4 __attribute__((ext_vector_type(4)));

__device__ __forceinline__ void async_copy16(const bf16_t* g, bf16_t* l) {
  __builtin_amdgcn_global_load_lds(
      (const __attribute__((address_space(1))) void*)g,
      (__attribute__((address_space(3))) void*)l, 16, 0, 0);
}

// ---------- converts ----------
struct CvtSeg { const float* s; bf16_t* d; long n; };
struct CvtArgs { CvtSeg seg[5]; };

__global__ void cvt_multi(CvtArgs a) {
  CvtSeg sg = a.seg[blockIdx.y];
#pragma unroll
  for (int it = 0; it < 4; it++) {
    long i = (((long)blockIdx.x + (long)it * 2048) * 256 + threadIdx.x) * 4;
    if (i < sg.n) {
      float4 f = *(const float4*)(sg.s + i);
      bf16x4 o;
      o[0] = (bf16_t)f.x; o[1] = (bf16_t)f.y; o[2] = (bf16_t)f.z; o[3] = (bf16_t)f.w;
      *(bf16x4*)(sg.d + i) = o;
    }
  }
}

// ---------- split-K half sum: mt = (bf16)(mh[2b] + mh[2b+1])  (r2-proven) ----------
__global__ void cvt_mhalf(const bf16_t* __restrict__ mh, bf16_t* __restrict__ mt) {
  const long i = ((long)blockIdx.x * 256 + threadIdx.x) * 8;  // 4M elems total
  const long b = i >> 20;              // output matrix index
  const long r = i & ((1L << 20) - 1);
  const bf16_t* h0 = mh + ((b * 2) << 20) + r;
  const bf16_t* h1 = h0 + (1L << 20);
  bf16x8 x0 = *(const bf16x8*)h0;
  bf16x8 x1 = *(const bf16x8*)h1;
  bf16x8 o;
#pragma unroll
  for (int j = 0; j < 8; j++) o[j] = (bf16_t)((float)x0[j] + (float)x1[j]);
  *(bf16x8*)(mt + i) = o;
}

// ---------- fused q / kT / vT: 128x128 tile, LDS dbuf (round-5 proven, ~60us) ----------
__global__ __launch_bounds__(256, 2) void qkv3(
    const bf16_t* __restrict__ xb,
    const bf16_t* __restrict__ Wq, const bf16_t* __restrict__ Wk, const bf16_t* __restrict__ Wv,
    const float* __restrict__ bq, const float* __restrict__ bk, const float* __restrict__ bv,
    bf16_t* __restrict__ qout, bf16_t* __restrict__ kT, bf16_t* __restrict__ vT) {
  __shared__ bf16_t As[2 * 4096];
  __shared__ bf16_t Bsh[3][2 * 4096];
  const int L = blockIdx.x;
  const int V = (L & 7) * 64 + (L >> 3);
  const int batch = V >> 7;
  const int rr_   = V & 127;
  const int n0 = (rr_ & 7) * 128;
  const int m0 = (rr_ >> 3) * 128;

  const int tid = threadIdx.x, lane = tid & 63, w = tid >> 6;
  const int wr = w >> 1, wc = w & 1, quad = lane >> 4, lm = lane & 15;
  const int ar = lane >> 2;
  const int ak = (((lane & 3) ^ ((ar >> 1) & 3))) * 8;
  const int swz = (lm >> 1) & 3;

  const bf16_t* ag0 = xb + (long)batch * (2048L * 1024) + (long)(m0 + w * 16 + ar) * 1024 + ak;
  const bf16_t* ag1 = ag0 + 64L * 1024;
  const bf16_t* Wp[3] = {Wq, Wk, Wv};
  const bf16_t* bg0[3];
  const bf16_t* bg1[3];
#pragma unroll
  for (int p = 0; p < 3; p++) {
    bg0[p] = Wp[p] + (long)(n0 + w * 16 + ar) * 1024 + ak;
    bg1[p] = bg0[p] + 64L * 1024;
  }

  floatx4 acc[3][4][4];
#pragma unroll
  for (int p = 0; p < 3; p++)
#pragma unroll
    for (int r = 0; r < 4; r++)
#pragma unroll
      for (int c = 0; c < 4; c++)
        acc[p][r][c] = (floatx4){0.f, 0.f, 0.f, 0.f};

  {
    bf16_t* la = As + w * 512;
    async_copy16(ag0, la);
    async_copy16(ag1, la + 2048);
#pragma unroll
    for (int p = 0; p < 3; p++) {
      bf16_t* lb = Bsh[p] + w * 512;
      async_copy16(bg0[p], lb);
      async_copy16(bg1[p], lb + 2048);
    }
  }
  for (int i = 0; i < 32; i++) {
    __syncthreads();
    if (i + 1 < 32) {
      const int buf = (i + 1) & 1, k0 = (i + 1) * 32;
      bf16_t* la = As + buf * 4096 + w * 512;
      async_copy16(ag0 + k0, la);
      async_copy16(ag1 + k0, la + 2048);
#pragma unroll
      for (int p = 0; p < 3; p++) {
        bf16_t* lb = Bsh[p] + buf * 4096 + w * 512;
        async_copy16(bg0[p] + k0, lb);
        async_copy16(bg1[p] + k0, lb + 2048);
      }
    }
    const bf16_t* Ar = As + (i & 1) * 4096;
    bf16x8 afr[4];
#pragma unroll
    for (int r = 0; r < 4; r++)
      afr[r] = *(const bf16x8*)&Ar[(wr * 64 + r * 16 + lm) * 32 + (quad ^ swz) * 8];
#pragma unroll
    for (int p = 0; p < 3; p++) {
      const bf16_t* Br = Bsh[p] + (i & 1) * 4096;
      bf16x8 bfr[4];
#pragma unroll
      for (int c = 0; c < 4; c++)
        bfr[c] = *(const bf16x8*)&Br[(wc * 64 + c * 16 + lm) * 32 + (quad ^ swz) * 8];
#pragma unroll
      for (int r = 0; r < 4; r++)
#pragma unroll
        for (int c = 0; c < 4; c++)
          acc[p][r][c] = __builtin_amdgcn_mfma_f32_16x16x32_bf16(afr[r], bfr[c], acc[p][r][c], 0, 0, 0);
    }
  }

  const int rowBase = m0 + wr * 64, colBase = n0 + wc * 64;
  {
    bf16_t* C = qout + (long)batch * (2048L * 1024);
#pragma unroll
    for (int r = 0; r < 4; r++) {
      const int row = rowBase + r * 16 + quad * 4;
#pragma unroll
      for (int c = 0; c < 4; c++) {
        const int col = colBase + c * 16 + lm;
        const float bv_ = bq[col];
#pragma unroll
        for (int i = 0; i < 4; i++)
          C[(long)(row + i) * 1024 + col] = (bf16_t)(acc[0][r][c][i] + bv_);
      }
    }
  }
#pragma unroll
  for (int p = 1; p < 3; p++) {
    bf16_t* C = ((p == 1) ? kT : vT) + (long)batch * (1024L * 2048);
    const float* bias = (p == 1) ? bk : bv;
#pragma unroll
    for (int r = 0; r < 4; r++) {
      const int row = rowBase + r * 16 + quad * 4;
#pragma unroll
      for (int c = 0; c < 4; c++) {
        const int col = colBase + c * 16 + lm;
        const float bv_ = bias[col];
        bf16x4 pk;
#pragma unroll
        for (int i = 0; i < 4; i++) pk[i] = (bf16_t)(acc[p][r][c][i] + bv_);
        *(bf16x4*)(C + (long)col * 2048 + row) = pk;
      }
    }
  }
}

// ---------- NT GEMM, 128x128, wave-private DEPTH-2 (64KB) + split-K ----------
// r3's proven barrier-free body + r2's koff/partial-index logic. 64KB LDS ->
// 2 blocks/CU when grid >= 512 (8 waves/CU: the TLP lever under test).
// Partials: C indexed by zz = batch*KSPLIT + kp, stride sC.
template<int OUT_MODE, bool HAS_BIAS, int TOTAL, int BPZ, int KSPLIT>
__global__ __launch_bounds__(256) void gemm_wp2(
    const bf16_t* __restrict__ A, const bf16_t* __restrict__ B,
    void* __restrict__ C, const float* __restrict__ bias,
    int lda, int ldb, int nk, long sA, long sB, long sC, int ldc, float alpha) {
  __shared__ bf16_t Ls[4 * 8192];   // 4 waves x (2 bufs x 4096 elems) = 64KB
  const int L = blockIdx.x;
  const int V = (L & 7) * (TOTAL / 8) + (L >> 3);
  const int zz = V / BPZ;
  const int r_ = V % BPZ;
  const int batch = zz / KSPLIT;
  const long koff = (long)(zz % KSPLIT) * ((long)nk * 32);
  const int n0 = (r_ & 7) * 128;
  const int m0 = (r_ >> 3) * 128;

  const int tid = threadIdx.x, lane = tid & 63, w = tid >> 6;
  const int wr = w >> 1, wc = w & 1, quad = lane >> 4, lm = lane & 15;
  const int ar = lane >> 2;
  const int ak = (((lane & 3) ^ ((ar >> 1) & 3))) * 8;
  const int swz = (lm >> 1) & 3;

  bf16_t* Lw = Ls + w * 8192;
  const bf16_t* Ab = A + (long)batch * sA + koff;
  const bf16_t* Bb = B + (long)batch * sB + koff;
  const bf16_t* agA = Ab + (long)(m0 + wr * 64 + ar) * lda + ak;
  const bf16_t* agB = Bb + (long)(n0 + wc * 64 + ar) * ldb + ak;

  auto STAGE = [&](int t, int b) {
    const int k0 = t * 32;
    bf16_t* d = Lw + b * 4096;
#pragma unroll
    for (int j = 0; j < 4; j++)
      async_copy16(agA + (long)j * 16 * lda + k0, d + j * 512);
#pragma unroll
    for (int j = 0; j < 4; j++)
      async_copy16(agB + (long)j * 16 * ldb + k0, d + 2048 + j * 512);
  };

  floatx4 acc[4][4];
#pragma unroll
  for (int r = 0; r < 4; r++)
#pragma unroll
    for (int c = 0; c < 4; c++) acc[r][c] = (floatx4){0.f, 0.f, 0.f, 0.f};

  STAGE(0, 0);
  for (int i = 0; i < nk; i++) {
    if (i + 1 < nk) {
      STAGE(i + 1, (i + 1) & 1);
      asm volatile("s_waitcnt vmcnt(8)" ::: "memory");  // tile i's 8 loads done
    } else {
      asm volatile("s_waitcnt vmcnt(0)" ::: "memory");
    }
    const bf16_t* Aw = Lw + (i & 1) * 4096;
    const bf16_t* Bw = Aw + 2048;
    bf16x8 afr[4], bfr[4];
#pragma unroll
    for (int r = 0; r < 4; r++)
      afr[r] = *(const bf16x8*)&Aw[(r * 16 + lm) * 32 + (quad ^ swz) * 8];
#pragma unroll
    for (int c = 0; c < 4; c++)
      bfr[c] = *(const bf16x8*)&Bw[(c * 16 + lm) * 32 + (quad ^ swz) * 8];
#pragma unroll
    for (int r = 0; r < 4; r++)
#pragma unroll
      for (int c = 0; c < 4; c++)
        acc[r][c] = __builtin_amdgcn_mfma_f32_16x16x32_bf16(afr[r], bfr[c], acc[r][c], 0, 0, 0);
  }

  const int rowBase = m0 + wr * 64, colBase = n0 + wc * 64;
  if (OUT_MODE == 0) {
    bf16_t* Cb = (bf16_t*)C + (long)zz * sC;
#pragma unroll
    for (int r = 0; r < 4; r++) {
      const int row = rowBase + r * 16 + quad * 4;
#pragma unroll
      for (int c = 0; c < 4; c++) {
        const int col = colBase + c * 16 + lm;
        const float bv_ = HAS_BIAS ? bias[col] : 0.f;
#pragma unroll
        for (int i = 0; i < 4; i++)
          Cb[(long)(row + i) * ldc + col] = (bf16_t)(acc[r][c][i] * alpha + bv_);
      }
    }
  } else {
    float* Cf = (float*)C + (long)zz * sC;
#pragma unroll
    for (int r = 0; r < 4; r++) {
      const int row = rowBase + r * 16 + quad * 4;
#pragma unroll
      for (int c = 0; c < 4; c++) {
        const int col = colBase + c * 16 + lm;
        const float bv_ = HAS_BIAS ? bias[col] : 0.f;
#pragma unroll
        for (int i = 0; i < 4; i++)
          Cf[(long)(row + i) * ldc + col] = acc[r][c][i] * alpha + bv_;
      }
    }
  }
}

// ---------- NT GEMM, 128x128, wave-private DEPTH-4 (128KB) — r5 champion verbatim ----------
template<int OUT_MODE, bool HAS_BIAS, int TOTAL, int BPZ>
__global__ __launch_bounds__(256) void gemm_wp(
    const bf16_t* __restrict__ A, const bf16_t* __restrict__ B,
    void* __restrict__ C, const float* __restrict__ bias,
    int lda, int ldb, int nk, long sA, long sB, long sC, int ldc, float alpha) {
  __shared__ bf16_t Ls[4 * 16384];  // 4 waves x 4 bufs x 4096 elems = 128KB static
  const int L = blockIdx.x;
  const int V = (L & 7) * (TOTAL / 8) + (L >> 3);
  const int batch = V / BPZ;
  const int r_ = V % BPZ;
  const int n0 = (r_ & 7) * 128;
  const int m0 = (r_ >> 3) * 128;

  const int tid = threadIdx.x, lane = tid & 63, w = tid >> 6;
  const int wr = w >> 1, wc = w & 1, quad = lane >> 4, lm = lane & 15;
  const int ar = lane >> 2;
  const int ak = (((lane & 3) ^ ((ar >> 1) & 3))) * 8;
  const int swz = (lm >> 1) & 3;

  bf16_t* Lw = Ls + w * 16384;
  const bf16_t* Ab = A + (long)batch * sA;
  const bf16_t* Bb = B + (long)batch * sB;
  const bf16_t* agA = Ab + (long)(m0 + wr * 64 + ar) * lda + ak;
  const bf16_t* agB = Bb + (long)(n0 + wc * 64 + ar) * ldb + ak;

  auto STAGE = [&](int t, int b) {
    const int k0 = t * 32;
    bf16_t* d = Lw + b * 4096;
#pragma unroll
    for (int j = 0; j < 4; j++)
      async_copy16(agA + (long)j * 16 * lda + k0, d + j * 512);
#pragma unroll
    for (int j = 0; j < 4; j++)
      async_copy16(agB + (long)j * 16 * ldb + k0, d + 2048 + j * 512);
  };

  floatx4 acc[4][4];
#pragma unroll
  for (int r = 0; r < 4; r++)
#pragma unroll
    for (int c = 0; c < 4; c++) acc[r][c] = (floatx4){0.f, 0.f, 0.f, 0.f};

  STAGE(0, 0);
  STAGE(1, 1);
  STAGE(2, 2);
  for (int i = 0; i < nk; i++) {
    const int rem = nk - 1 - i;
    if (rem >= 3) {
      STAGE(i + 3, (i + 3) & 3);
      asm volatile("s_waitcnt vmcnt(24)" ::: "memory");
    } else if (rem == 2) {
      asm volatile("s_waitcnt vmcnt(16)" ::: "memory");
    } else if (rem == 1) {
      asm volatile("s_waitcnt vmcnt(8)" ::: "memory");
    } else {
      asm volatile("s_waitcnt vmcnt(0)" ::: "memory");
    }
    const bf16_t* Aw = Lw + (i & 3) * 4096;
    const bf16_t* Bw = Aw + 2048;
    bf16x8 afr[4], bfr[4];
#pragma unroll
    for (int r = 0; r < 4; r++)
      afr[r] = *(const bf16x8*)&Aw[(r * 16 + lm) * 32 + (quad ^ swz) * 8];
#pragma unroll
    for (int c = 0; c < 4; c++)
      bfr[c] = *(const bf16x8*)&Bw[(c * 16 + lm) * 32 + (quad ^ swz) * 8];
#pragma unroll
    for (int r = 0; r < 4; r++)
#pragma unroll
      for (int c = 0; c < 4; c++)
        acc[r][c] = __builtin_amdgcn_mfma_f32_16x16x32_bf16(afr[r], bfr[c], acc[r][c], 0, 0, 0);
  }

  const int rowBase = m0 + wr * 64, colBase = n0 + wc * 64;
  if (OUT_MODE == 0) {
    bf16_t* Cb = (bf16_t*)C + (long)batch * sC;
#pragma unroll
    for (int r = 0; r < 4; r++) {
      const int row = rowBase + r * 16 + quad * 4;
#pragma unroll
      for (int c = 0; c < 4; c++) {
        const int col = colBase + c * 16 + lm;
        const float bv_ = HAS_BIAS ? bias[col] : 0.f;
#pragma unroll
        for (int i = 0; i < 4; i++)
          Cb[(long)(row + i) * ldc + col] = (bf16_t)(acc[r][c][i] * alpha + bv_);
      }
    }
  } else {
    float* Cf = (float*)C + (long)batch * sC;
#pragma unroll
    for (int r = 0; r < 4; r++) {
      const int row = rowBase + r * 16 + quad * 4;
#pragma unroll
      for (int c = 0; c < 4; c++) {
        const int col = colBase + c * 16 + lm;
        const float bv_ = HAS_BIAS ? bias[col] : 0.f;
#pragma unroll
        for (int i = 0; i < 4; i++)
          Cf[(long)(row + i) * ldc + col] = acc[r][c][i] * alpha + bv_;
      }
    }
  }
}

extern "C" void kernel_launch(void* const* d_in, const int* in_sizes, int n_in,
                              void* d_out, int out_size, void* d_ws, size_t ws_size,
                              hipStream_t stream) {
  const float* x  = (const float*)d_in[0];
  const float* Wq = (const float*)d_in[1];
  const float* bq = (const float*)d_in[2];
  const float* Wk = (const float*)d_in[3];
  const float* bk = (const float*)d_in[4];
  const float* Wv = (const float*)d_in[5];
  const float* bv = (const float*)d_in[6];
  const float* Wo = (const float*)d_in[7];
  const float* bo = (const float*)d_in[8];
  float* out = (float*)d_out;

  const long NX = 8192L * 1024;      // 8M elems
  const long NW = 1024L * 1024;      // 1M elems

  bf16_t* ws  = (bf16_t*)d_ws;
  bf16_t* xb  = ws;                  // NX
  bf16_t* Wqb = xb + NX;
  bf16_t* Wkb = Wqb + NW;
  bf16_t* Wvb = Wkb + NW;
  bf16_t* Wob = Wvb + NW;
  bf16_t* qb  = Wob + NW;            // NX
  bf16_t* kT  = qb + NX;             // NX [B][E][S]
  bf16_t* vT  = kT + NX;             // NX [B][E][S]
  // reuse (stream-ordered):
  bf16_t* Mh   = xb;                 // 8M: [z=b*2+kp][f][e] partials (xb dead after qkv3)
  bf16_t* MtTb = kT;                 // 4M: [B][f][e] (kT dead after M gemm)
  bf16_t* Gb   = vT;                 // 4M: [B][i][f] (vT dead after M gemm)

  CvtArgs ca;
  ca.seg[0] = {x,  xb,  NX};
  ca.seg[1] = {Wq, Wqb, NW};
  ca.seg[2] = {Wk, Wkb, NW};
  ca.seg[3] = {Wv, Wvb, NW};
  ca.seg[4] = {Wo, Wob, NW};
  cvt_multi<<<dim3(2048, 5), 256, 0, stream>>>(ca);

  // q / kT / vT fused, 128x128, 2 blocks/CU (round-5 proven: ~60us)
  qkv3<<<dim3(512), 256, 0, stream>>>(xb, Wqb, Wkb, Wvb, bq, bk, bv, qb, kT, vT);

  // MtT partials: z = b*2+kp, each 0.125 * sum over K-half; 512 blocks -> 2 blk/CU
  gemm_wp2<0, false, 512, 64, 2><<<dim3(512), 256, 0, stream>>>(
      kT, vT, Mh, nullptr, 2048, 2048, 32,
      1024L * 2048, 1024L * 2048, 1024L * 1024, 1024, 0.125f);

  // MtTb = Mh[2b] + Mh[2b+1]
  cvt_mhalf<<<dim3(2048), 256, 0, stream>>>(Mh, MtTb);

  // G[i,f] = sum_e Wo[i,e] * MtT[f,e]; 256 blocks (r5 verbatim, d4)
  gemm_wp<0, false, 256, 64><<<dim3(256), 256, 0, stream>>>(
      Wob, MtTb, Gb, nullptr, 1024, 1024, 32,
      0L, 1024L * 1024, 1024L * 1024, 1024, 1.0f);

  // out[s,i] = sum_f q[s,f] * G[i,f] + bo[i]; 512 blocks (r5 verbatim, d4)
  gemm_wp<2, true, 512, 128><<<dim3(512), 256, 0, stream>>>(
      qb, Gb, out, bo, 1024, 1024, 32,
      2048L * 1024, 1024L * 1024, 2048L * 1024, 1024, 1.0f);
}